// Round 12
// baseline (470.958 us; speedup 1.0000x reference)
//
#include <hip/hip_runtime.h>
#include <hip/hip_bf16.h>
#include <cstdint>
#include <cstddef>

#define DM   1024
#define VG   2048
#define QKD  128
#define NB   8
#define SEQ  2048
#define NH   4224      // 2*VG + QKD
#define MTOT 16384     // NB*SEQ
#define CH   1024      // attention query-row chunk per batch (P overlays xb)

typedef __bf16 bf16;
typedef __attribute__((ext_vector_type(4))) __bf16 bf16x4;
typedef __attribute__((ext_vector_type(8))) __bf16 bf16x8;
typedef __attribute__((ext_vector_type(4))) float f32x4;
typedef __attribute__((ext_vector_type(16))) float f32x16;

__device__ __forceinline__ void gload16(void* lds, const void* g) {
  __builtin_amdgcn_global_load_lds(
      (const __attribute__((address_space(1))) uint32_t*)g,
      (__attribute__((address_space(3))) uint32_t*)lds, 16, 0, 0);
}

#define FENCE() asm volatile("" ::: "memory")
#define BAR()  do { FENCE(); __builtin_amdgcn_s_barrier(); FENCE(); } while (0)

// ===========================================================================
// Core A: 128x128, BK=64, 4 waves (2x2), 2-barrier loop, XOR-swizzled LDS.
// ===========================================================================

__device__ __forceinline__ void gemm128_core(const bf16* __restrict__ Ab,
                                             const bf16* __restrict__ Bb,
                                             int K, f32x4 (&acc)[4][4]) {
  __shared__ alignas(16) bf16 lsA[128 * 64];
  __shared__ alignas(16) bf16 lsB[128 * 64];
  const int t    = threadIdx.x;
  const int lane = t & 63;
  const int wid  = t >> 6;
  const int wr   = wid >> 1;
  const int wc   = wid & 1;
  const int lr   = lane & 15;
  const int sk   = lane >> 4;

#pragma unroll
  for (int m = 0; m < 4; ++m)
#pragma unroll
    for (int n = 0; n < 4; ++n)
      acc[m][n] = f32x4{0.f, 0.f, 0.f, 0.f};

  for (int k0 = 0; k0 < K; k0 += 64) {
#pragma unroll
    for (int i = 0; i < 4; ++i) {
      const int flat = i * 256 + t;
      const int r = flat >> 3;
      const int sl = (flat & 7) ^ (r & 7);
      gload16(lsA + (size_t)flat * 8, Ab + (size_t)r * K + k0 + sl * 8);
      gload16(lsB + (size_t)flat * 8, Bb + (size_t)r * K + k0 + sl * 8);
    }
    __syncthreads();
#pragma unroll
    for (int kk3 = 0; kk3 < 8; kk3 += 4) {
      bf16x8 af[4], bfr[4];
#pragma unroll
      for (int m = 0; m < 4; ++m) {
        const int r = wr * 64 + m * 16 + lr;
        af[m] = *(const bf16x8*)&lsA[r * 64 + (((kk3 + sk) ^ (r & 7)) << 3)];
      }
#pragma unroll
      for (int n = 0; n < 4; ++n) {
        const int r = wc * 64 + n * 16 + lr;
        bfr[n] = *(const bf16x8*)&lsB[r * 64 + (((kk3 + sk) ^ (r & 7)) << 3)];
      }
#pragma unroll
      for (int m = 0; m < 4; ++m)
#pragma unroll
        for (int n = 0; n < 4; ++n)
          acc[m][n] = __builtin_amdgcn_mfma_f32_16x16x32_bf16(af[m], bfr[n], acc[m][n], 0, 0, 0);
    }
    __syncthreads();
  }
}

// ===========================================================================
// Core C32: 256x128, BK=64, 8 waves (4M x 2N), 2-barrier loop, 48 KiB LDS,
// 32x32x16 MFMA. r11 ERRATA: slot^(r&7) left rows {c,c+8,c+16,c+24} (same
// hi-half, same r&7) on the SAME slot -> 4-way bank conflict (1.73e7 cyc).
// Fix: slot_phys = slot_log ^ (r&7) ^ ((r>>3)&3) — the added term enumerates
// the 4 aliasing rows onto 4 distinct slots; per-row map stays bijective;
// wave slot distribution uniform (8 lanes/slot, the conflict-free pattern).
// Applied identically to staging source and read address (rule #21).
// ===========================================================================

__device__ __forceinline__ int swz32(int slot, int r) {
  return slot ^ (r & 7) ^ ((r >> 3) & 3);
}

__device__ __forceinline__ void gemm256x128_core32(const bf16* __restrict__ Ab,
                                                   const bf16* __restrict__ Bb,
                                                   int K, f32x16 (&acc)[2][2]) {
  __shared__ alignas(16) bf16 lsA[256 * 64];
  __shared__ alignas(16) bf16 lsB[128 * 64];
  const int t    = threadIdx.x;       // 0..511
  const int lane = t & 63;
  const int wid  = t >> 6;            // 0..7
  const int wr   = wid >> 1;          // 0..3 (M quarter)
  const int wc   = wid & 1;           // 0..1 (N half)
  const int r32  = lane & 31;         // fragment row
  const int hi   = lane >> 5;         // k-subgroup (8 elems)

#pragma unroll
  for (int m = 0; m < 2; ++m)
#pragma unroll
    for (int n = 0; n < 2; ++n)
#pragma unroll
      for (int j = 0; j < 16; ++j)
        acc[m][n][j] = 0.f;

  for (int k0 = 0; k0 < K; k0 += 64) {
#pragma unroll
    for (int i = 0; i < 4; ++i) {     // A: 2048 chunks / 512 thr
      const int flat = i * 512 + t;
      const int r = flat >> 3;        // 0..255
      const int sl = swz32(flat & 7, r);
      gload16(lsA + (size_t)flat * 8, Ab + (size_t)r * K + k0 + sl * 8);
    }
#pragma unroll
    for (int i = 0; i < 2; ++i) {     // B: 1024 chunks / 512 thr
      const int flat = i * 512 + t;
      const int r = flat >> 3;        // 0..127
      const int sl = swz32(flat & 7, r);
      gload16(lsB + (size_t)flat * 8, Bb + (size_t)r * K + k0 + sl * 8);
    }
    __syncthreads();
#pragma unroll
    for (int ki = 0; ki < 4; ++ki) {  // k-slice of 16
      const int slot = 2 * ki + hi;   // logical 16B slot (k/8)
      bf16x8 af[2], bfr[2];
#pragma unroll
      for (int m = 0; m < 2; ++m) {
        const int r = wr * 64 + m * 32 + r32;     // 0..255
        af[m] = *(const bf16x8*)&lsA[r * 64 + (swz32(slot, r) << 3)];
      }
#pragma unroll
      for (int n = 0; n < 2; ++n) {
        const int r = wc * 64 + n * 32 + r32;     // 0..127
        bfr[n] = *(const bf16x8*)&lsB[r * 64 + (swz32(slot, r) << 3)];
      }
#pragma unroll
      for (int m = 0; m < 2; ++m)
#pragma unroll
        for (int n = 0; n < 2; ++n)
          acc[m][n] = __builtin_amdgcn_mfma_f32_32x32x16_bf16(af[m], bfr[n], acc[m][n], 0, 0, 0);
    }
    __syncthreads();
  }
}

// ===========================================================================
// Core B: 256x256, BK=64, 8 waves, 8-phase pipeline — gemmO / gemm2.
// ===========================================================================

__device__ __forceinline__ void stage_half(bf16* dst, const bf16* __restrict__ src,
                                           int K, int k0, int rbase) {
  const int t = threadIdx.x;
#pragma unroll
  for (int i = 0; i < 2; ++i) {
    const int c = i * 512 + t;
    const int r = c >> 3;
    const int l = (c & 7) ^ (r & 7);
    gload16(dst + (size_t)c * 8, src + (size_t)(rbase + r) * K + k0 + l * 8);
  }
}

__device__ __forceinline__ void rd_a(bf16x8 (&fa)[4][2], const bf16* p,
                                     int wr, int lr, int kg, int mbase) {
#pragma unroll
  for (int m = 0; m < 4; ++m) {
    const int r = wr * 128 + (mbase + m) * 16 + lr;
#pragma unroll
    for (int ks = 0; ks < 2; ++ks)
      fa[m][ks] = *(const bf16x8*)&p[r * 64 + ((((ks << 2) + kg) ^ (r & 7)) << 3)];
  }
}

__device__ __forceinline__ void rd_b(bf16x8 (&fb)[2][2], const bf16* p,
                                     int wc, int lr, int kg, int nbase) {
#pragma unroll
  for (int n = 0; n < 2; ++n) {
    const int r = wc * 64 + (nbase + n) * 16 + lr;
#pragma unroll
    for (int ks = 0; ks < 2; ++ks)
      fb[n][ks] = *(const bf16x8*)&p[r * 64 + ((((ks << 2) + kg) ^ (r & 7)) << 3)];
  }
}

__device__ __forceinline__ void mfma16(f32x4 (&acc)[8][4], const bf16x8 (&fa)[4][2],
                                       const bf16x8 (&fb)[2][2], int mb, int nb) {
  __builtin_amdgcn_s_setprio(1);
#pragma unroll
  for (int m = 0; m < 4; ++m)
#pragma unroll
    for (int n = 0; n < 2; ++n)
#pragma unroll
      for (int ks = 0; ks < 2; ++ks)
        acc[mb + m][nb + n] = __builtin_amdgcn_mfma_f32_16x16x32_bf16(
            fa[m][ks], fb[n][ks], acc[mb + m][nb + n], 0, 0, 0);
  __builtin_amdgcn_s_setprio(0);
}

__device__ __forceinline__ void gemm256_core(const bf16* __restrict__ Ab,
                                             const bf16* __restrict__ Bb,
                                             int K, f32x4 (&acc)[8][4]) {
  __shared__ alignas(16) bf16 lds[2][2][256 * 64];
  const int lane = threadIdx.x & 63;
  const int wid  = threadIdx.x >> 6;
  const int wr   = wid >> 2, wc = wid & 3;
  const int lr   = lane & 15;
  const int kg   = lane >> 4;
  const int HS   = 128 * 64;

#pragma unroll
  for (int m = 0; m < 8; ++m)
#pragma unroll
    for (int n = 0; n < 4; ++n)
      acc[m][n] = f32x4{0.f, 0.f, 0.f, 0.f};

  const int NT = K >> 6;
  stage_half(lds[0][1], Bb, K, 0, 0);  stage_half(lds[0][1] + HS, Bb, K, 0, 128);
  stage_half(lds[0][0], Ab, K, 0, 0);  stage_half(lds[0][0] + HS, Ab, K, 0, 128);
  stage_half(lds[1][1], Bb, K, 64, 0); stage_half(lds[1][1] + HS, Bb, K, 64, 128);
  asm volatile("s_waitcnt vmcnt(4)" ::: "memory");
  BAR();

  for (int ti = 0; ti < NT; ti += 2) {
    const bool more = (ti + 2 < NT);
#pragma unroll
    for (int g = 0; g < 2; ++g) {
      const int tc = ti + g;
      const bf16* pA = lds[g][0];
      const bf16* pB = lds[g][1];
      bf16* sA = lds[g ^ 1][0];
      bf16* sB = lds[g][1];
      const bool stA = (g == 0) || more;
      const int kA = (tc + 1) << 6;
      const int kB = (tc + 2) << 6;
      bf16x8 fa[4][2], fb0[2][2], fb1[2][2];

      rd_a(fa, pA, wr, lr, kg, 0);
      rd_b(fb0, pB, wc, lr, kg, 0);
      if (stA) stage_half(sA, Ab, K, kA, 0);
      BAR();
      mfma16(acc, fa, fb0, 0, 0);
      BAR();

      rd_b(fb1, pB, wc, lr, kg, 2);
      if (stA) stage_half(sA + HS, Ab, K, kA, 128);
      BAR();
      mfma16(acc, fa, fb1, 0, 2);
      BAR();

      rd_a(fa, pA, wr, lr, kg, 4);
      if (more) stage_half(sB, Bb, K, kB, 0);
      BAR();
      mfma16(acc, fa, fb0, 4, 0);
      BAR();

      if (more) {
        stage_half(sB + HS, Bb, K, kB, 128);
        asm volatile("s_waitcnt vmcnt(4)" ::: "memory");
      } else {
        asm volatile("s_waitcnt vmcnt(0)" ::: "memory");
      }
      BAR();
      mfma16(acc, fa, fb1, 4, 2);
      BAR();
    }
  }
}

// ---------------- conversion / transpose ----------------

__global__ __launch_bounds__(256)
void k_cvt(const float* __restrict__ in, bf16* __restrict__ out, int n8) {
  const int i = blockIdx.x * 256 + threadIdx.x;
  if (i >= n8) return;
  const float* p = in + (size_t)i * 8;
  bf16x8 o;
#pragma unroll
  for (int j = 0; j < 8; ++j) o[j] = (bf16)p[j];
  *(bf16x8*)(out + (size_t)i * 8) = o;
}

__global__ __launch_bounds__(256)
void k_transpose(const float* __restrict__ in, bf16* __restrict__ out, int R, int C) {
  __shared__ float tile[64][65];
  const int r0 = blockIdx.y * 64, c0 = blockIdx.x * 64;
  const int t = threadIdx.x;
#pragma unroll
  for (int i = 0; i < 16; ++i) {
    const int flat = i * 256 + t;
    const int r = flat >> 6, c = flat & 63;
    tile[r][c] = in[(size_t)(r0 + r) * C + (c0 + c)];
  }
  __syncthreads();
#pragma unroll
  for (int i = 0; i < 16; ++i) {
    const int flat = i * 256 + t;
    const int r = flat >> 6, c = flat & 63;
    out[(size_t)(c0 + r) * R + (r0 + c)] = (bf16)tile[c][r];
  }
}

// ---------------- mask -> bitmask (one 32-bit word per 32 keys) ----------------

__global__ __launch_bounds__(256)
void k_maskbits(const int* __restrict__ pm, uint32_t* __restrict__ mbits) {
  const int idx = blockIdx.x * 256 + threadIdx.x;   // 0..NB*SEQ/32-1
  if (idx >= NB * SEQ / 32) return;
  const int* p = pm + (size_t)idx * 32;
  uint32_t w = 0;
#pragma unroll
  for (int j = 0; j < 32; ++j) w |= (p[j] != 0 ? 1u : 0u) << j;
  mbits[idx] = w;
}

// ---------------- GEMM1 (core C32): h = x@W_i + b_i ; SiLU ; split ----------------
// C/D mapping (m74/m101): col = nfbase + (lane&31),
//   row = mfbase + (reg&3) + 8*(reg>>2) + 4*(lane>>5), reg in [0,16).

__global__ __launch_bounds__(512, 2)
void k_gemm1(const bf16* __restrict__ xb, const bf16* __restrict__ wibt,
             const float* __restrict__ b_i,
             const float* __restrict__ q_w, const float* __restrict__ q_b,
             const float* __restrict__ k_w, const float* __restrict__ k_b,
             bf16* __restrict__ u, bf16* __restrict__ vT,
             bf16* __restrict__ q, bf16* __restrict__ k) {
  const int orig  = blockIdx.x;              // 0..2111
  const int local = orig >> 3;               // 0..263
  const int mblk  = (orig & 7) * 8 + (local & 7);  // 0..63
  const int nblk  = local >> 3;              // 0..32
  const int bm0 = mblk * 256, bn0 = nblk * 128;
  f32x16 acc[2][2];
  gemm256x128_core32(xb + (size_t)bm0 * DM, wibt + (size_t)bn0 * DM, DM, acc);
  const int lane = threadIdx.x & 63;
  const int wid  = threadIdx.x >> 6;
  const int wr = wid >> 1, wc = wid & 1;
  const int r32 = lane & 31, hi = lane >> 5;
  const float rs = 0.08838834764831845f;     // 1/sqrt(128)
#pragma unroll
  for (int mf = 0; mf < 2; ++mf)
#pragma unroll
    for (int nf = 0; nf < 2; ++nf) {
      const int col = bn0 + wc * 64 + nf * 32 + r32;
      const int rbase = bm0 + wr * 64 + mf * 32 + 4 * hi;
#pragma unroll
      for (int g = 0; g < 4; ++g) {
        const int r0 = rbase + 8 * g;        // rows r0..r0+3 = regs 4g..4g+3
        float s[4];
#pragma unroll
        for (int j = 0; j < 4; ++j) {
          const float h = acc[mf][nf][4 * g + j] + b_i[col];
          s[j] = h / (1.f + __expf(-h));     // silu
        }
        if (col < VG) {
#pragma unroll
          for (int j = 0; j < 4; ++j)
            u[(size_t)(r0 + j) * VG + col] = (bf16)s[j];
        } else if (col < 2 * VG) {
          const int c = col - VG;
          const int b = r0 >> 11, rr = r0 & 2047;   // r0 % 4 == 0
          bf16x4 v4;
#pragma unroll
          for (int j = 0; j < 4; ++j) v4[j] = (bf16)s[j];
          *(bf16x4*)&vT[((size_t)b * VG + c) * SEQ + rr] = v4;
        } else {
          const int c = col - 2 * VG;
#pragma unroll
          for (int j = 0; j < 4; ++j) {
            q[(size_t)(r0 + j) * QKD + c] = (bf16)((s[j] * q_w[c] + q_b[c]) * rs);
            k[(size_t)(r0 + j) * QKD + c] = (bf16)(s[j] * k_w[c] + k_b[c]);
          }
        }
      }
    }
}

// ---------------- S-chunk = q[m0:m0+CH] @ k^T (core A; K=128) ----------------

__global__ __launch_bounds__(256, 2)
void k_gemmS(const bf16* __restrict__ q, const bf16* __restrict__ k,
             bf16* __restrict__ P, int m0) {
  const int b   = blockIdx.z;
  const int bm0 = blockIdx.y * 128;
  const int bn0 = blockIdx.x * 128;
  f32x4 acc[4][4];
  gemm128_core(q + ((size_t)b * SEQ + m0 + bm0) * QKD,
               k + ((size_t)b * SEQ + bn0) * QKD, QKD, acc);
  bf16* Pb = P + (size_t)b * CH * SEQ;
  const int lane = threadIdx.x & 63;
  const int wid  = threadIdx.x >> 6;
  const int wr = wid >> 1, wc = wid & 1;
#pragma unroll
  for (int m = 0; m < 4; ++m)
#pragma unroll
    for (int n = 0; n < 4; ++n)
#pragma unroll
      for (int j = 0; j < 4; ++j) {
        const int row = bm0 + wr * 64 + m * 16 + ((lane >> 4) << 2) + j;
        const int col = bn0 + wc * 64 + n * 16 + (lane & 15);
        Pb[(size_t)row * SEQ + col] = (bf16)acc[m][n][j];
      }
}

// ---------------- wave-per-row softmax (in place), bitmask-masked ----------------

__global__ __launch_bounds__(256)
void k_softmax(bf16* __restrict__ P, const uint32_t* __restrict__ mbits) {
  const int row  = blockIdx.x * 4 + (threadIdx.x >> 6);  // 0..NB*CH-1
  const int b    = row >> 10;                            // row / CH
  const int lane = threadIdx.x & 63;
  bf16* srow = P + (size_t)row * SEQ;

  bf16x8 v[4];
  float f[4][8];
  float mx = -1e30f;
#pragma unroll
  for (int i = 0; i < 4; ++i) {
    v[i] = *(const bf16x8*)(srow + i * 512 + lane * 8);
    const uint32_t w = mbits[b * 64 + i * 16 + (lane >> 2)];
    const uint32_t byte = (w >> ((lane & 3) * 8)) & 0xFFu;
#pragma unroll
    for (int j = 0; j < 8; ++j) {
      f[i][j] = ((byte >> j) & 1u) ? (float)v[i][j] : -1e30f;
      mx = fmaxf(mx, f[i][j]);
    }
  }
#pragma unroll
  for (int off = 32; off > 0; off >>= 1) mx = fmaxf(mx, __shfl_xor(mx, off));
  float sum = 0.f;
#pragma unroll
  for (int i = 0; i < 4; ++i)
#pragma unroll
    for (int j = 0; j < 8; ++j) {
      f[i][j] = (f[i][j] > -1e29f) ? __expf(f[i][j] - mx) : 0.f;
      sum += f[i][j];
    }
#pragma unroll
  for (int off = 32; off > 0; off >>= 1) sum += __shfl_xor(sum, off);
  const float inv = 1.f / sum;
#pragma unroll
  for (int i = 0; i < 4; ++i) {
#pragma unroll
    for (int j = 0; j < 8; ++j) v[i][j] = (bf16)(f[i][j] * inv);
    *(bf16x8*)(srow + i * 512 + lane * 8) = v[i];
  }
}

// ---------------- o = u .* (P @ v), over u in place (core B) ----------------

__global__ __launch_bounds__(512, 2)
void k_gemmO(const bf16* __restrict__ P, const bf16* __restrict__ vT,
             bf16* uo, int m0) {
  int wg = blockIdx.x;                       // 256 = 8b x 4m x 8n
  wg = (wg & 7) * 32 + (wg >> 3);
  const int b   = wg >> 5;
  const int bm0 = ((wg >> 3) & 3) * 256;
  const int bn0 = (wg & 7) * 256;
  f32x4 acc[8][4];
  gemm256_core(P + ((size_t)b * CH + bm0) * SEQ,
               vT + ((size_t)b * VG + bn0) * SEQ, SEQ, acc);
  const int lane = threadIdx.x & 63;
  const int wid  = threadIdx.x >> 6;
  const int wr = wid >> 2, wc = wid & 3;
#pragma unroll
  for (int m = 0; m < 8; ++m)
#pragma unroll
    for (int n = 0; n < 4; ++n)
#pragma unroll
      for (int j = 0; j < 4; ++j) {
        const int row = bm0 + wr * 128 + m * 16 + ((lane >> 4) << 2) + j;
        const int col = bn0 + wc * 64 + n * 16 + (lane & 15);
        const size_t idx = ((size_t)(b * SEQ + m0 + row)) * VG + col;
        uo[idx] = (bf16)(acc[m][n][j] * (float)uo[idx]);
      }
}

// ---------------- out = o @ W_o + b_o (fp32 out, core B) ----------------

__global__ __launch_bounds__(512, 2)
void k_gemm2(const bf16* __restrict__ o, const bf16* __restrict__ wobt,
             const float* __restrict__ b_o, float* __restrict__ out) {
  int wg = blockIdx.x;                       // 256 = 64m x 4n
  wg = (wg & 7) * 32 + (wg >> 3);
  const int bm0 = (wg >> 2) * 256;
  const int bn0 = (wg & 3) * 256;
  f32x4 acc[8][4];
  gemm256_core(o + (size_t)bm0 * VG, wobt + (size_t)bn0 * VG, VG, acc);
  const int lane = threadIdx.x & 63;
  const int wid  = threadIdx.x >> 6;
  const int wr = wid >> 2, wc = wid & 3;
#pragma unroll
  for (int m = 0; m < 8; ++m)
#pragma unroll
    for (int n = 0; n < 4; ++n)
#pragma unroll
      for (int j = 0; j < 4; ++j) {
        const int row = bm0 + wr * 128 + m * 16 + ((lane >> 4) << 2) + j;
        const int col = bn0 + wc * 64 + n * 16 + (lane & 15);
        out[(size_t)row * DM + col] = acc[m][n][j] + b_o[col];
      }
}

// ---------------- launch ----------------
// Workspace (~189 MB + 4KB): wobt 4.2 | xb/P 33.6 | wibt 8.7 | qb 4.2
//                            | kb 4.2 | uo 67.1 | vT 67.1 | mbits 4KB

extern "C" void kernel_launch(void* const* d_in, const int* in_sizes, int n_in,
                              void* d_out, int out_size, void* d_ws, size_t ws_size,
                              hipStream_t stream) {
  const float* x   = (const float*)d_in[0];
  const int*   pm  = (const int*)d_in[1];
  const float* W_i = (const float*)d_in[2];
  const float* b_i = (const float*)d_in[3];
  const float* q_w = (const float*)d_in[4];
  const float* q_b = (const float*)d_in[5];
  const float* k_w = (const float*)d_in[6];
  const float* k_b = (const float*)d_in[7];
  const float* W_o = (const float*)d_in[8];
  const float* b_o = (const float*)d_in[9];
  float* out = (float*)d_out;

  char* w = (char*)d_ws;
  bf16* wobt = (bf16*)w; w += (size_t)DM * VG * 2;
  bf16* xb   = (bf16*)w; w += (size_t)MTOT * DM * 2;   // reused as P chunk
  bf16* wibt = (bf16*)w; w += (size_t)NH * DM * 2;
  bf16* qb   = (bf16*)w; w += (size_t)MTOT * QKD * 2;
  bf16* kb   = (bf16*)w; w += (size_t)MTOT * QKD * 2;
  bf16* uo   = (bf16*)w; w += (size_t)MTOT * VG * 2;   // u, then o (in place)
  bf16* vT   = (bf16*)w; w += (size_t)MTOT * VG * 2;   // v^T per batch [VG][SEQ]
  uint32_t* mbits = (uint32_t*)w; w += 4096;
  bf16* Pc   = xb;

  // x -> bf16
  k_cvt<<<dim3(MTOT * DM / 8 / 256), 256, 0, stream>>>(x, xb, MTOT * DM / 8);
  // padding mask -> bitmask (512 words)
  k_maskbits<<<dim3(2), 256, 0, stream>>>(pm, mbits);
  // W_i (DM x NH) -> (NH x DM) bf16 ; W_o (VG x DM) -> (DM x VG) bf16
  k_transpose<<<dim3(NH / 64, DM / 64), 256, 0, stream>>>(W_i, wibt, DM, NH);
  k_transpose<<<dim3(DM / 64, VG / 64), 256, 0, stream>>>(W_o, wobt, VG, DM);
  // GEMM1 + silu + split (v written pre-transposed; xb dead afterwards)
  k_gemm1<<<dim3(2112), 512, 0, stream>>>(
      xb, wibt, b_i, q_w, q_b, k_w, k_b, uo, vT, qb, kb);
  // attention in CH-row chunks; P overlays xb
  for (int c = 0; c < SEQ / CH; ++c) {
    const int m0 = c * CH;
    k_gemmS<<<dim3(SEQ / 128, CH / 128, NB), 256, 0, stream>>>(qb, kb, Pc, m0);
    k_softmax<<<dim3(NB * CH / 4), 256, 0, stream>>>(Pc, mbits);
    k_gemmO<<<dim3(NB * 4 * 8), 512, 0, stream>>>(Pc, vT, uo, m0);
  }
  // out = o @ W_o + b_o
  k_gemm2<<<dim3(64 * 4), 512, 0, stream>>>(uo, wobt, b_o, out);
}

// Round 13
// 438.560 us; speedup vs baseline: 1.0739x; 1.0739x over previous
//
#include <hip/hip_runtime.h>
#include <hip/hip_bf16.h>
#include <cstdint>
#include <cstddef>

#define DM   1024
#define VG   2048
#define QKD  128
#define NB   8
#define SEQ  2048
#define NH   4224      // 2*VG + QKD
#define MTOT 16384     // NB*SEQ
#define CH   1024      // attention query-row chunk per batch (P overlays xb)

typedef __bf16 bf16;
typedef __attribute__((ext_vector_type(4))) __bf16 bf16x4;
typedef __attribute__((ext_vector_type(8))) __bf16 bf16x8;
typedef __attribute__((ext_vector_type(4))) float f32x4;

__device__ __forceinline__ void gload16(void* lds, const void* g) {
  __builtin_amdgcn_global_load_lds(
      (const __attribute__((address_space(1))) uint32_t*)g,
      (__attribute__((address_space(3))) uint32_t*)lds, 16, 0, 0);
}

#define FENCE() asm volatile("" ::: "memory")
#define BAR()  do { FENCE(); __builtin_amdgcn_s_barrier(); FENCE(); } while (0)

// ===========================================================================
// Core A: 128x128, BK=64, 4 waves (2x2), 2-barrier loop, XOR-swizzled LDS.
// ===========================================================================

__device__ __forceinline__ void gemm128_core(const bf16* __restrict__ Ab,
                                             const bf16* __restrict__ Bb,
                                             int K, f32x4 (&acc)[4][4]) {
  __shared__ alignas(16) bf16 lsA[128 * 64];
  __shared__ alignas(16) bf16 lsB[128 * 64];
  const int t    = threadIdx.x;
  const int lane = t & 63;
  const int wid  = t >> 6;
  const int wr   = wid >> 1;
  const int wc   = wid & 1;
  const int lr   = lane & 15;
  const int sk   = lane >> 4;

#pragma unroll
  for (int m = 0; m < 4; ++m)
#pragma unroll
    for (int n = 0; n < 4; ++n)
      acc[m][n] = f32x4{0.f, 0.f, 0.f, 0.f};

  for (int k0 = 0; k0 < K; k0 += 64) {
#pragma unroll
    for (int i = 0; i < 4; ++i) {
      const int flat = i * 256 + t;
      const int r = flat >> 3;
      const int sl = (flat & 7) ^ (r & 7);
      gload16(lsA + (size_t)flat * 8, Ab + (size_t)r * K + k0 + sl * 8);
      gload16(lsB + (size_t)flat * 8, Bb + (size_t)r * K + k0 + sl * 8);
    }
    __syncthreads();
#pragma unroll
    for (int kk3 = 0; kk3 < 8; kk3 += 4) {
      bf16x8 af[4], bfr[4];
#pragma unroll
      for (int m = 0; m < 4; ++m) {
        const int r = wr * 64 + m * 16 + lr;
        af[m] = *(const bf16x8*)&lsA[r * 64 + (((kk3 + sk) ^ (r & 7)) << 3)];
      }
#pragma unroll
      for (int n = 0; n < 4; ++n) {
        const int r = wc * 64 + n * 16 + lr;
        bfr[n] = *(const bf16x8*)&lsB[r * 64 + (((kk3 + sk) ^ (r & 7)) << 3)];
      }
#pragma unroll
      for (int m = 0; m < 4; ++m)
#pragma unroll
        for (int n = 0; n < 4; ++n)
          acc[m][n] = __builtin_amdgcn_mfma_f32_16x16x32_bf16(af[m], bfr[n], acc[m][n], 0, 0, 0);
    }
    __syncthreads();
  }
}

// ===========================================================================
// Core C: 256x128, BK=64, 8 waves (4M x 2N), 2-barrier loop, 48 KiB LDS.
// Measured best for gemm1 (r10: 177 us, MfmaUtil 36%, conflicts 0).
// r11/r12 A/B: 32x32x16 MFMA variant is slower even conflict-free (192 vs
// 177) — longer per-inst pipe occupancy reduces wave-interleave slack.
// ===========================================================================

__device__ __forceinline__ void gemm256x128_core(const bf16* __restrict__ Ab,
                                                 const bf16* __restrict__ Bb,
                                                 int K, f32x4 (&acc)[4][4]) {
  __shared__ alignas(16) bf16 lsA[256 * 64];
  __shared__ alignas(16) bf16 lsB[128 * 64];
  const int t    = threadIdx.x;       // 0..511
  const int lane = t & 63;
  const int wid  = t >> 6;            // 0..7
  const int wr   = wid >> 1;          // 0..3 (M quarter)
  const int wc   = wid & 1;           // 0..1 (N half)
  const int lr   = lane & 15;
  const int sk   = lane >> 4;

#pragma unroll
  for (int m = 0; m < 4; ++m)
#pragma unroll
    for (int n = 0; n < 4; ++n)
      acc[m][n] = f32x4{0.f, 0.f, 0.f, 0.f};

  for (int k0 = 0; k0 < K; k0 += 64) {
#pragma unroll
    for (int i = 0; i < 4; ++i) {     // A: 2048 chunks / 512 thr
      const int flat = i * 512 + t;
      const int r = flat >> 3;        // 0..255
      const int sl = (flat & 7) ^ (r & 7);
      gload16(lsA + (size_t)flat * 8, Ab + (size_t)r * K + k0 + sl * 8);
    }
#pragma unroll
    for (int i = 0; i < 2; ++i) {     // B: 1024 chunks / 512 thr
      const int flat = i * 512 + t;
      const int r = flat >> 3;        // 0..127
      const int sl = (flat & 7) ^ (r & 7);
      gload16(lsB + (size_t)flat * 8, Bb + (size_t)r * K + k0 + sl * 8);
    }
    __syncthreads();
#pragma unroll
    for (int kk3 = 0; kk3 < 8; kk3 += 4) {
      bf16x8 af[4], bfr[4];
#pragma unroll
      for (int m = 0; m < 4; ++m) {
        const int r = wr * 64 + m * 16 + lr;   // 0..255
        af[m] = *(const bf16x8*)&lsA[r * 64 + (((kk3 + sk) ^ (r & 7)) << 3)];
      }
#pragma unroll
      for (int n = 0; n < 4; ++n) {
        const int r = wc * 64 + n * 16 + lr;   // 0..127
        bfr[n] = *(const bf16x8*)&lsB[r * 64 + (((kk3 + sk) ^ (r & 7)) << 3)];
      }
#pragma unroll
      for (int m = 0; m < 4; ++m)
#pragma unroll
        for (int n = 0; n < 4; ++n)
          acc[m][n] = __builtin_amdgcn_mfma_f32_16x16x32_bf16(af[m], bfr[n], acc[m][n], 0, 0, 0);
    }
    __syncthreads();
  }
}

// ===========================================================================
// Core B: 256x256, BK=64, 8 waves, 8-phase pipeline — gemmO / gemm2.
// ===========================================================================

__device__ __forceinline__ void stage_half(bf16* dst, const bf16* __restrict__ src,
                                           int K, int k0, int rbase) {
  const int t = threadIdx.x;
#pragma unroll
  for (int i = 0; i < 2; ++i) {
    const int c = i * 512 + t;
    const int r = c >> 3;
    const int l = (c & 7) ^ (r & 7);
    gload16(dst + (size_t)c * 8, src + (size_t)(rbase + r) * K + k0 + l * 8);
  }
}

__device__ __forceinline__ void rd_a(bf16x8 (&fa)[4][2], const bf16* p,
                                     int wr, int lr, int kg, int mbase) {
#pragma unroll
  for (int m = 0; m < 4; ++m) {
    const int r = wr * 128 + (mbase + m) * 16 + lr;
#pragma unroll
    for (int ks = 0; ks < 2; ++ks)
      fa[m][ks] = *(const bf16x8*)&p[r * 64 + ((((ks << 2) + kg) ^ (r & 7)) << 3)];
  }
}

__device__ __forceinline__ void rd_b(bf16x8 (&fb)[2][2], const bf16* p,
                                     int wc, int lr, int kg, int nbase) {
#pragma unroll
  for (int n = 0; n < 2; ++n) {
    const int r = wc * 64 + (nbase + n) * 16 + lr;
#pragma unroll
    for (int ks = 0; ks < 2; ++ks)
      fb[n][ks] = *(const bf16x8*)&p[r * 64 + ((((ks << 2) + kg) ^ (r & 7)) << 3)];
  }
}

__device__ __forceinline__ void mfma16(f32x4 (&acc)[8][4], const bf16x8 (&fa)[4][2],
                                       const bf16x8 (&fb)[2][2], int mb, int nb) {
  __builtin_amdgcn_s_setprio(1);
#pragma unroll
  for (int m = 0; m < 4; ++m)
#pragma unroll
    for (int n = 0; n < 2; ++n)
#pragma unroll
      for (int ks = 0; ks < 2; ++ks)
        acc[mb + m][nb + n] = __builtin_amdgcn_mfma_f32_16x16x32_bf16(
            fa[m][ks], fb[n][ks], acc[mb + m][nb + n], 0, 0, 0);
  __builtin_amdgcn_s_setprio(0);
}

__device__ __forceinline__ void gemm256_core(const bf16* __restrict__ Ab,
                                             const bf16* __restrict__ Bb,
                                             int K, f32x4 (&acc)[8][4]) {
  __shared__ alignas(16) bf16 lds[2][2][256 * 64];
  const int lane = threadIdx.x & 63;
  const int wid  = threadIdx.x >> 6;
  const int wr   = wid >> 2, wc = wid & 3;
  const int lr   = lane & 15;
  const int kg   = lane >> 4;
  const int HS   = 128 * 64;

#pragma unroll
  for (int m = 0; m < 8; ++m)
#pragma unroll
    for (int n = 0; n < 4; ++n)
      acc[m][n] = f32x4{0.f, 0.f, 0.f, 0.f};

  const int NT = K >> 6;
  stage_half(lds[0][1], Bb, K, 0, 0);  stage_half(lds[0][1] + HS, Bb, K, 0, 128);
  stage_half(lds[0][0], Ab, K, 0, 0);  stage_half(lds[0][0] + HS, Ab, K, 0, 128);
  stage_half(lds[1][1], Bb, K, 64, 0); stage_half(lds[1][1] + HS, Bb, K, 64, 128);
  asm volatile("s_waitcnt vmcnt(4)" ::: "memory");
  BAR();

  for (int ti = 0; ti < NT; ti += 2) {
    const bool more = (ti + 2 < NT);
#pragma unroll
    for (int g = 0; g < 2; ++g) {
      const int tc = ti + g;
      const bf16* pA = lds[g][0];
      const bf16* pB = lds[g][1];
      bf16* sA = lds[g ^ 1][0];
      bf16* sB = lds[g][1];
      const bool stA = (g == 0) || more;
      const int kA = (tc + 1) << 6;
      const int kB = (tc + 2) << 6;
      bf16x8 fa[4][2], fb0[2][2], fb1[2][2];

      rd_a(fa, pA, wr, lr, kg, 0);
      rd_b(fb0, pB, wc, lr, kg, 0);
      if (stA) stage_half(sA, Ab, K, kA, 0);
      BAR();
      mfma16(acc, fa, fb0, 0, 0);
      BAR();

      rd_b(fb1, pB, wc, lr, kg, 2);
      if (stA) stage_half(sA + HS, Ab, K, kA, 128);
      BAR();
      mfma16(acc, fa, fb1, 0, 2);
      BAR();

      rd_a(fa, pA, wr, lr, kg, 4);
      if (more) stage_half(sB, Bb, K, kB, 0);
      BAR();
      mfma16(acc, fa, fb0, 4, 0);
      BAR();

      if (more) {
        stage_half(sB + HS, Bb, K, kB, 128);
        asm volatile("s_waitcnt vmcnt(4)" ::: "memory");
      } else {
        asm volatile("s_waitcnt vmcnt(0)" ::: "memory");
      }
      BAR();
      mfma16(acc, fa, fb1, 4, 2);
      BAR();
    }
  }
}

// ---------------- conversion / transpose ----------------

__global__ __launch_bounds__(256)
void k_cvt(const float* __restrict__ in, bf16* __restrict__ out, int n8) {
  const int i = blockIdx.x * 256 + threadIdx.x;
  if (i >= n8) return;
  const float* p = in + (size_t)i * 8;
  bf16x8 o;
#pragma unroll
  for (int j = 0; j < 8; ++j) o[j] = (bf16)p[j];
  *(bf16x8*)(out + (size_t)i * 8) = o;
}

__global__ __launch_bounds__(256)
void k_transpose(const float* __restrict__ in, bf16* __restrict__ out, int R, int C) {
  __shared__ float tile[64][65];
  const int r0 = blockIdx.y * 64, c0 = blockIdx.x * 64;
  const int t = threadIdx.x;
#pragma unroll
  for (int i = 0; i < 16; ++i) {
    const int flat = i * 256 + t;
    const int r = flat >> 6, c = flat & 63;
    tile[r][c] = in[(size_t)(r0 + r) * C + (c0 + c)];
  }
  __syncthreads();
#pragma unroll
  for (int i = 0; i < 16; ++i) {
    const int flat = i * 256 + t;
    const int r = flat >> 6, c = flat & 63;
    out[(size_t)(c0 + r) * R + (r0 + c)] = (bf16)tile[c][r];
  }
}

// ---------------- mask -> bitmask (one 32-bit word per 32 keys) ----------------

__global__ __launch_bounds__(256)
void k_maskbits(const int* __restrict__ pm, uint32_t* __restrict__ mbits) {
  const int idx = blockIdx.x * 256 + threadIdx.x;   // 0..NB*SEQ/32-1
  if (idx >= NB * SEQ / 32) return;
  const int* p = pm + (size_t)idx * 32;
  uint32_t w = 0;
#pragma unroll
  for (int j = 0; j < 32; ++j) w |= (p[j] != 0 ? 1u : 0u) << j;
  mbits[idx] = w;
}

// ---------------- GEMM1 (core C): h = x@W_i + b_i ; SiLU ; split ----------------
// Grid 2112 = 64M x 33N (256x128 tiles). XCD x owns M-blocks [8x, 8x+8);
// within-XCD order n-major inner-m: the XCD's 4.2 MB A-strip stays
// L2-resident across all 33 N-steps (FETCH 370->117 MB measured r8->r9).

__global__ __launch_bounds__(512, 2)
void k_gemm1(const bf16* __restrict__ xb, const bf16* __restrict__ wibt,
             const float* __restrict__ b_i,
             const float* __restrict__ q_w, const float* __restrict__ q_b,
             const float* __restrict__ k_w, const float* __restrict__ k_b,
             bf16* __restrict__ u, bf16* __restrict__ vT,
             bf16* __restrict__ q, bf16* __restrict__ k) {
  const int orig  = blockIdx.x;              // 0..2111
  const int local = orig >> 3;               // 0..263
  const int mblk  = (orig & 7) * 8 + (local & 7);  // 0..63
  const int nblk  = local >> 3;              // 0..32
  const int bm0 = mblk * 256, bn0 = nblk * 128;
  f32x4 acc[4][4];
  gemm256x128_core(xb + (size_t)bm0 * DM, wibt + (size_t)bn0 * DM, DM, acc);
  const int lane = threadIdx.x & 63;
  const int wid  = threadIdx.x >> 6;
  const int wr = wid >> 1, wc = wid & 1;
  const float rs = 0.08838834764831845f;     // 1/sqrt(128)
#pragma unroll
  for (int m = 0; m < 4; ++m)
#pragma unroll
    for (int n = 0; n < 4; ++n) {
      const int rb  = bm0 + wr * 64 + m * 16 + ((lane >> 4) << 2);  // j=0 row
      const int col = bn0 + wc * 64 + n * 16 + (lane & 15);
      float s[4];
#pragma unroll
      for (int j = 0; j < 4; ++j) {
        const float h = acc[m][n][j] + b_i[col];
        s[j] = h / (1.f + __expf(-h));       // silu
      }
      if (col < VG) {
#pragma unroll
        for (int j = 0; j < 4; ++j)
          u[(size_t)(rb + j) * VG + col] = (bf16)s[j];
      } else if (col < 2 * VG) {
        const int c = col - VG;
        const int b = rb >> 11, rr = rb & 2047;
        bf16x4 v4;
#pragma unroll
        for (int j = 0; j < 4; ++j) v4[j] = (bf16)s[j];
        *(bf16x4*)&vT[((size_t)b * VG + c) * SEQ + rr] = v4;
      } else {
        const int c = col - 2 * VG;
#pragma unroll
        for (int j = 0; j < 4; ++j) {
          q[(size_t)(rb + j) * QKD + c] = (bf16)((s[j] * q_w[c] + q_b[c]) * rs);
          k[(size_t)(rb + j) * QKD + c] = (bf16)(s[j] * k_w[c] + k_b[c]);
        }
      }
    }
}

// ---------------- S-chunk = q[m0:m0+CH] @ k^T (core A; K=128) ----------------

__global__ __launch_bounds__(256, 2)
void k_gemmS(const bf16* __restrict__ q, const bf16* __restrict__ k,
             bf16* __restrict__ P, int m0) {
  const int b   = blockIdx.z;
  const int bm0 = blockIdx.y * 128;
  const int bn0 = blockIdx.x * 128;
  f32x4 acc[4][4];
  gemm128_core(q + ((size_t)b * SEQ + m0 + bm0) * QKD,
               k + ((size_t)b * SEQ + bn0) * QKD, QKD, acc);
  bf16* Pb = P + (size_t)b * CH * SEQ;
  const int lane = threadIdx.x & 63;
  const int wid  = threadIdx.x >> 6;
  const int wr = wid >> 1, wc = wid & 1;
#pragma unroll
  for (int m = 0; m < 4; ++m)
#pragma unroll
    for (int n = 0; n < 4; ++n)
#pragma unroll
      for (int j = 0; j < 4; ++j) {
        const int row = bm0 + wr * 64 + m * 16 + ((lane >> 4) << 2) + j;
        const int col = bn0 + wc * 64 + n * 16 + (lane & 15);
        Pb[(size_t)row * SEQ + col] = (bf16)acc[m][n][j];
      }
}

// ---------------- wave-per-row softmax (in place), bitmask-masked ----------------

__global__ __launch_bounds__(256)
void k_softmax(bf16* __restrict__ P, const uint32_t* __restrict__ mbits) {
  const int row  = blockIdx.x * 4 + (threadIdx.x >> 6);  // 0..NB*CH-1
  const int b    = row >> 10;                            // row / CH
  const int lane = threadIdx.x & 63;
  bf16* srow = P + (size_t)row * SEQ;

  bf16x8 v[4];
  float f[4][8];
  float mx = -1e30f;
#pragma unroll
  for (int i = 0; i < 4; ++i) {
    v[i] = *(const bf16x8*)(srow + i * 512 + lane * 8);
    const uint32_t w = mbits[b * 64 + i * 16 + (lane >> 2)];
    const uint32_t byte = (w >> ((lane & 3) * 8)) & 0xFFu;
#pragma unroll
    for (int j = 0; j < 8; ++j) {
      f[i][j] = ((byte >> j) & 1u) ? (float)v[i][j] : -1e30f;
      mx = fmaxf(mx, f[i][j]);
    }
  }
#pragma unroll
  for (int off = 32; off > 0; off >>= 1) mx = fmaxf(mx, __shfl_xor(mx, off));
  float sum = 0.f;
#pragma unroll
  for (int i = 0; i < 4; ++i)
#pragma unroll
    for (int j = 0; j < 8; ++j) {
      f[i][j] = (f[i][j] > -1e29f) ? __expf(f[i][j] - mx) : 0.f;
      sum += f[i][j];
    }
#pragma unroll
  for (int off = 32; off > 0; off >>= 1) sum += __shfl_xor(sum, off);
  const float inv = 1.f / sum;
#pragma unroll
  for (int i = 0; i < 4; ++i) {
#pragma unroll
    for (int j = 0; j < 8; ++j) v[i][j] = (bf16)(f[i][j] * inv);
    *(bf16x8*)(srow + i * 512 + lane * 8) = v[i];
  }
}

// ---------------- o = u .* (P @ v), over u in place (core B) ----------------

__global__ __launch_bounds__(512, 2)
void k_gemmO(const bf16* __restrict__ P, const bf16* __restrict__ vT,
             bf16* uo, int m0) {
  int wg = blockIdx.x;                       // 256 = 8b x 4m x 8n
  wg = (wg & 7) * 32 + (wg >> 3);
  const int b   = wg >> 5;
  const int bm0 = ((wg >> 3) & 3) * 256;
  const int bn0 = (wg & 7) * 256;
  f32x4 acc[8][4];
  gemm256_core(P + ((size_t)b * CH + bm0) * SEQ,
               vT + ((size_t)b * VG + bn0) * SEQ, SEQ, acc);
  const int lane = threadIdx.x & 63;
  const int wid  = threadIdx.x >> 6;
  const int wr = wid >> 2, wc = wid & 3;
#pragma unroll
  for (int m = 0; m < 8; ++m)
#pragma unroll
    for (int n = 0; n < 4; ++n)
#pragma unroll
      for (int j = 0; j < 4; ++j) {
        const int row = bm0 + wr * 128 + m * 16 + ((lane >> 4) << 2) + j;
        const int col = bn0 + wc * 64 + n * 16 + (lane & 15);
        const size_t idx = ((size_t)(b * SEQ + m0 + row)) * VG + col;
        uo[idx] = (bf16)(acc[m][n][j] * (float)uo[idx]);
      }
}

// ---------------- out = o @ W_o + b_o (fp32 out, core B) ----------------

__global__ __launch_bounds__(512, 2)
void k_gemm2(const bf16* __restrict__ o, const bf16* __restrict__ wobt,
             const float* __restrict__ b_o, float* __restrict__ out) {
  int wg = blockIdx.x;                       // 256 = 64m x 4n
  wg = (wg & 7) * 32 + (wg >> 3);
  const int bm0 = (wg >> 2) * 256;
  const int bn0 = (wg & 3) * 256;
  f32x4 acc[8][4];
  gemm256_core(o + (size_t)bm0 * VG, wobt + (size_t)bn0 * VG, VG, acc);
  const int lane = threadIdx.x & 63;
  const int wid  = threadIdx.x >> 6;
  const int wr = wid >> 2, wc = wid & 3;
#pragma unroll
  for (int m = 0; m < 8; ++m)
#pragma unroll
    for (int n = 0; n < 4; ++n)
#pragma unroll
      for (int j = 0; j < 4; ++j) {
        const int row = bm0 + wr * 128 + m * 16 + ((lane >> 4) << 2) + j;
        const int col = bn0 + wc * 64 + n * 16 + (lane & 15);
        out[(size_t)row * DM + col] = acc[m][n][j] + b_o[col];
      }
}

// ---------------- launch ----------------
// Workspace (~189 MB + 4KB): wobt 4.2 | xb/P 33.6 | wibt 8.7 | qb 4.2
//                            | kb 4.2 | uo 67.1 | vT 67.1 | mbits 4KB

extern "C" void kernel_launch(void* const* d_in, const int* in_sizes, int n_in,
                              void* d_out, int out_size, void* d_ws, size_t ws_size,
                              hipStream_t stream) {
  const float* x   = (const float*)d_in[0];
  const int*   pm  = (const int*)d_in[1];
  const float* W_i = (const float*)d_in[2];
  const float* b_i = (const float*)d_in[3];
  const float* q_w = (const float*)d_in[4];
  const float* q_b = (const float*)d_in[5];
  const float* k_w = (const float*)d_in[6];
  const float* k_b = (const float*)d_in[7];
  const float* W_o = (const float*)d_in[8];
  const float* b_o = (const float*)d_in[9];
  float* out = (float*)d_out;

  char* w = (char*)d_ws;
  bf16* wobt = (bf16*)w; w += (size_t)DM * VG * 2;
  bf16* xb   = (bf16*)w; w += (size_t)MTOT * DM * 2;   // reused as P chunk
  bf16* wibt = (bf16*)w; w += (size_t)NH * DM * 2;
  bf16* qb   = (bf16*)w; w += (size_t)MTOT * QKD * 2;
  bf16* kb   = (bf16*)w; w += (size_t)MTOT * QKD * 2;
  bf16* uo   = (bf16*)w; w += (size_t)MTOT * VG * 2;   // u, then o (in place)
  bf16* vT   = (bf16*)w; w += (size_t)MTOT * VG * 2;   // v^T per batch [VG][SEQ]
  uint32_t* mbits = (uint32_t*)w; w += 4096;
  bf16* Pc   = xb;

  // x -> bf16
  k_cvt<<<dim3(MTOT * DM / 8 / 256), 256, 0, stream>>>(x, xb, MTOT * DM / 8);
  // padding mask -> bitmask (512 words)
  k_maskbits<<<dim3(2), 256, 0, stream>>>(pm, mbits);
  // W_i (DM x NH) -> (NH x DM) bf16 ; W_o (VG x DM) -> (DM x VG) bf16
  k_transpose<<<dim3(NH / 64, DM / 64), 256, 0, stream>>>(W_i, wibt, DM, NH);
  k_transpose<<<dim3(DM / 64, VG / 64), 256, 0, stream>>>(W_o, wobt, VG, DM);
  // GEMM1 + silu + split (v written pre-transposed; xb dead afterwards)
  k_gemm1<<<dim3(2112), 512, 0, stream>>>(
      xb, wibt, b_i, q_w, q_b, k_w, k_b, uo, vT, qb, kb);
  // attention in CH-row chunks; P overlays xb
  for (int c = 0; c < SEQ / CH; ++c) {
    const int m0 = c * CH;
    k_gemmS<<<dim3(SEQ / 128, CH / 128, NB), 256, 0, stream>>>(qb, kb, Pc, m0);
    k_softmax<<<dim3(NB * CH / 4), 256, 0, stream>>>(Pc, mbits);
    k_gemmO<<<dim3(NB * 4 * 8), 512, 0, stream>>>(Pc, vT, uo, m0);
  }
  // out = o @ W_o + b_o
  k_gemm2<<<dim3(64 * 4), 512, 0, stream>>>(uo, wobt, b_o, out);
}